// Round 1
// baseline (248.815 us; speedup 1.0000x reference)
//
#include <hip/hip_runtime.h>

#define BATCH 8
#define NCLS 21
#define H 512
#define W 512
#define IGNORE_INDEX 255
#define HW (H * W)
#define NPIX (BATCH * H * W)

__global__ void zero_out_kernel(float* out) {
    if (threadIdx.x == 0 && blockIdx.x == 0) out[0] = 0.0f;
}

// One thread per (h, w). boundary(h,w) = 1 iff interior and any batch b,
// any column w' in {w-1,w,w+1} has the 3 row values not all equal.
__global__ void boundary_kernel(const int* __restrict__ t,
                                unsigned char* __restrict__ bmap) {
    int idx = blockIdx.x * blockDim.x + threadIdx.x;
    if (idx >= HW) return;
    int h = idx / W;
    int w = idx % W;
    unsigned char bd = 0;
    if (h > 0 && h < H - 1 && w > 0 && w < W - 1) {
        for (int b = 0; b < BATCH && !bd; ++b) {
            const int* base = t + b * HW;
            #pragma unroll
            for (int dw = -1; dw <= 1; ++dw) {
                int ww = w + dw;
                int a = base[(h - 1) * W + ww];
                int m = base[h * W + ww];
                int c = base[(h + 1) * W + ww];
                if ((a != m) | (m != c)) { bd = 1; break; }
            }
        }
    }
    bmap[idx] = bd;
}

__global__ __launch_bounds__(256)
void ce_kernel(const float* __restrict__ x, const int* __restrict__ t,
               const unsigned char* __restrict__ bmap,
               float* __restrict__ out) {
    float local = 0.0f;
    const int stride = gridDim.x * blockDim.x;
    for (int idx = blockIdx.x * blockDim.x + threadIdx.x; idx < NPIX;
         idx += stride) {
        int b = idx / HW;
        int hw = idx - b * HW;
        const float* p = x + (size_t)b * NCLS * HW + hw;

        int tg = t[idx];
        bool valid = (tg != IGNORE_INDEX);
        int st = valid ? tg : 0;

        float v[NCLS];
        #pragma unroll
        for (int c = 0; c < NCLS; ++c) v[c] = p[(size_t)c * HW];

        float m = v[0];
        #pragma unroll
        for (int c = 1; c < NCLS; ++c) m = fmaxf(m, v[c]);

        float s = 0.0f;
        float xt = v[0];
        #pragma unroll
        for (int c = 0; c < NCLS; ++c) {
            s += __expf(v[c] - m);
            if (c == st) xt = v[c];   // select chain, no dynamic reg indexing
        }
        float ce = __logf(s) + m - xt;
        ce = valid ? ce : 0.0f;

        float wgt = 1.0f + 2.0f * (float)bmap[hw];
        local += ce * wgt;
    }

    // wave reduce (64 lanes)
    #pragma unroll
    for (int off = 32; off > 0; off >>= 1)
        local += __shfl_down(local, off, 64);

    __shared__ float smem[4];  // 256 threads / 64
    int lane = threadIdx.x & 63;
    int wave = threadIdx.x >> 6;
    if (lane == 0) smem[wave] = local;
    __syncthreads();
    if (threadIdx.x == 0) {
        float bsum = smem[0] + smem[1] + smem[2] + smem[3];
        atomicAdd(out, bsum * (1.0f / (float)NPIX));
    }
}

extern "C" void kernel_launch(void* const* d_in, const int* in_sizes, int n_in,
                              void* d_out, int out_size, void* d_ws, size_t ws_size,
                              hipStream_t stream) {
    const float* x = (const float*)d_in[0];
    const int* t = (const int*)d_in[1];
    float* out = (float*)d_out;
    unsigned char* bmap = (unsigned char*)d_ws;  // HW bytes = 256 KB

    zero_out_kernel<<<1, 64, 0, stream>>>(out);

    boundary_kernel<<<(HW + 255) / 256, 256, 0, stream>>>(t, bmap);

    ce_kernel<<<2048, 256, 0, stream>>>(x, t, bmap, out);
}

// Round 2
// 244.912 us; speedup vs baseline: 1.0159x; 1.0159x over previous
//
#include <hip/hip_runtime.h>

#define BATCH 8
#define NCLS 21
#define H 512
#define W 512
#define IGNORE_INDEX 255
#define HW (H * W)
#define NPIX (BATCH * H * W)

// One thread per (h, w). boundary(h,w) = 1 iff interior and any batch b,
// any column w' in {w-1,w,w+1} has the 3 row values not all equal.
// Thread 0 also zeroes the output (d_out is 0xAA-poisoned before each replay);
// stream order guarantees this completes before ce_kernel's atomicAdd.
__global__ void boundary_kernel(const int* __restrict__ t,
                                unsigned char* __restrict__ bmap,
                                float* __restrict__ out) {
    int idx = blockIdx.x * blockDim.x + threadIdx.x;
    if (idx == 0) out[0] = 0.0f;
    if (idx >= HW) return;
    int h = idx >> 9;        // / W
    int w = idx & (W - 1);   // % W
    unsigned char bd = 0;
    if (h > 0 && h < H - 1 && w > 0 && w < W - 1) {
        for (int b = 0; b < BATCH && !bd; ++b) {
            const int* base = t + b * HW;
            #pragma unroll
            for (int dw = -1; dw <= 1; ++dw) {
                int ww = w + dw;
                int a = base[(h - 1) * W + ww];
                int m = base[h * W + ww];
                int c = base[(h + 1) * W + ww];
                if ((a != m) | (m != c)) { bd = 1; break; }
            }
        }
    }
    bmap[idx] = bd;
}

__device__ __forceinline__ float ce_one(const float* __restrict__ v, int tg,
                                        unsigned int bd) {
    bool valid = (tg != IGNORE_INDEX);
    int st = valid ? tg : 0;
    float m = v[0];
    #pragma unroll
    for (int c = 1; c < NCLS; ++c) m = fmaxf(m, v[c]);
    float s = 0.0f;
    float xt = v[0];
    #pragma unroll
    for (int c = 0; c < NCLS; ++c) {
        s += __expf(v[c] - m);
        if (c == st) xt = v[c];  // constant c -> cndmask chain, no scratch
    }
    float ce = __logf(s) + m - xt;
    ce = valid ? ce : 0.0f;
    return ce * (1.0f + 2.0f * (float)bd);
}

// 4 pixels per thread via float4 loads. NPIX/4 = 524288 threads exactly.
__global__ __launch_bounds__(256)
void ce_kernel(const float* __restrict__ x, const int* __restrict__ t,
               const unsigned char* __restrict__ bmap,
               float* __restrict__ out) {
    int tid = blockIdx.x * blockDim.x + threadIdx.x;
    int idx4 = tid << 2;
    int b = idx4 >> 18;          // / HW (pow2)
    int hw = idx4 & (HW - 1);    // % HW; hw+3 < HW always (idx4 % 4 == 0)
    const float* p = x + (size_t)b * NCLS * HW + hw;

    int4 tg = *(const int4*)(t + idx4);
    uchar4 bm = *(const uchar4*)(bmap + hw);

    float v0[NCLS], v1[NCLS], v2[NCLS], v3[NCLS];
    #pragma unroll
    for (int c = 0; c < NCLS; ++c) {
        float4 q = *(const float4*)(p + (size_t)c * HW);  // 16B aligned
        v0[c] = q.x; v1[c] = q.y; v2[c] = q.z; v3[c] = q.w;
    }

    float local = ce_one(v0, tg.x, bm.x) + ce_one(v1, tg.y, bm.y) +
                  ce_one(v2, tg.z, bm.z) + ce_one(v3, tg.w, bm.w);

    // wave reduce (64 lanes)
    #pragma unroll
    for (int off = 32; off > 0; off >>= 1)
        local += __shfl_down(local, off, 64);

    __shared__ float smem[4];
    int lane = threadIdx.x & 63;
    int wave = threadIdx.x >> 6;
    if (lane == 0) smem[wave] = local;
    __syncthreads();
    if (threadIdx.x == 0) {
        float bsum = smem[0] + smem[1] + smem[2] + smem[3];
        atomicAdd(out, bsum * (1.0f / (float)NPIX));
    }
}

extern "C" void kernel_launch(void* const* d_in, const int* in_sizes, int n_in,
                              void* d_out, int out_size, void* d_ws, size_t ws_size,
                              hipStream_t stream) {
    const float* x = (const float*)d_in[0];
    const int* t = (const int*)d_in[1];
    float* out = (float*)d_out;
    unsigned char* bmap = (unsigned char*)d_ws;  // HW bytes = 256 KB

    boundary_kernel<<<(HW + 255) / 256, 256, 0, stream>>>(t, bmap, out);
    ce_kernel<<<NPIX / 4 / 256, 256, 0, stream>>>(x, t, bmap, out);
}

// Round 4
// 235.728 us; speedup vs baseline: 1.0555x; 1.0390x over previous
//
#include <hip/hip_runtime.h>

#define BATCH 8
#define NCLS 21
#define H 512
#define W 512
#define IGNORE_INDEX 255
#define HW (H * W)
#define NPIX (BATCH * HW)
#define NBLK 2048   // NPIX / 4 / 256

typedef float vfloat4 __attribute__((ext_vector_type(4)));

__device__ __forceinline__ float ce_one(const float* __restrict__ v, int tg,
                                        unsigned int bd) {
    bool valid = (tg != IGNORE_INDEX);
    int st = valid ? tg : 0;
    float m = v[0];
    #pragma unroll
    for (int c = 1; c < NCLS; ++c) m = fmaxf(m, v[c]);
    float s = 0.0f;
    float xt = v[0];
    #pragma unroll
    for (int c = 0; c < NCLS; ++c) {
        s += __expf(v[c] - m);
        if (c == st) xt = v[c];  // constant c -> cndmask chain, no scratch
    }
    float ce = __logf(s) + m - xt;
    ce = valid ? ce : 0.0f;
    return ce * (1.0f + 2.0f * (float)bd);
}

// One fused kernel: 4 pixels/thread (same batch, consecutive w), boundary
// recomputed inline from targets (cache-resident, hidden under logit HBM
// stream; with random targets the early-exit loop resolves at batch 0 for
// nearly all pixels). Block partial sums written to ws — no atomics, no
// output zero-init needed.
__global__ __launch_bounds__(256)
void fused_kernel(const float* __restrict__ x, const int* __restrict__ t,
                  float* __restrict__ partial) {
    int tid = blockIdx.x * blockDim.x + threadIdx.x;
    int idx4 = tid << 2;
    int b = idx4 >> 18;          // / HW
    int hw = idx4 & (HW - 1);    // % HW
    int h = hw >> 9;             // / W
    int w = hw & (W - 1);        // % W  (multiple of 4)

    // boundary bits for pixels (h, w..w+3); reference: bd(h,w) = OR over
    // batch, OR over cols w-1..w+1 of [3-row column not all equal].
    unsigned bd0 = 0, bd1 = 0, bd2 = 0, bd3 = 0;
    if (h > 0 && h < H - 1) {
        #pragma unroll 1
        for (int bb = 0; bb < BATCH; ++bb) {
            const int* r1 = t + bb * HW + h * W;  // middle row
            unsigned cd[6];
            #pragma unroll
            for (int c = 0; c < 6; ++c) {
                int col = w - 1 + c;
                col = col < 0 ? 0 : (col > W - 1 ? W - 1 : col);  // clamp;
                // clamped cols only feed bd0/bd3 which get forced 0 below
                int a = r1[col - W];
                int mm = r1[col];
                int z = r1[col + W];
                cd[c] = (unsigned)((a != mm) | (mm != z));
            }
            bd0 |= cd[0] | cd[1] | cd[2];
            bd1 |= cd[1] | cd[2] | cd[3];
            bd2 |= cd[2] | cd[3] | cd[4];
            bd3 |= cd[3] | cd[4] | cd[5];
            if (bd0 & bd1 & bd2 & bd3) break;
        }
        if (w == 0) bd0 = 0;        // pixel j=0 at w==0 is border
        if (w == W - 4) bd3 = 0;    // pixel j=3 at w==511 is border
    }

    int4 tg = *(const int4*)(t + idx4);

    const float* p = x + (size_t)b * NCLS * HW + hw;
    float v0[NCLS], v1[NCLS], v2[NCLS], v3[NCLS];
    #pragma unroll
    for (int c = 0; c < NCLS; ++c) {
        vfloat4 q = __builtin_nontemporal_load((const vfloat4*)(p + (size_t)c * HW));
        v0[c] = q.x; v1[c] = q.y; v2[c] = q.z; v3[c] = q.w;
    }

    float local = ce_one(v0, tg.x, bd0) + ce_one(v1, tg.y, bd1) +
                  ce_one(v2, tg.z, bd2) + ce_one(v3, tg.w, bd3);

    #pragma unroll
    for (int off = 32; off > 0; off >>= 1)
        local += __shfl_down(local, off, 64);

    __shared__ float smem[4];
    int lane = threadIdx.x & 63;
    int wave = threadIdx.x >> 6;
    if (lane == 0) smem[wave] = local;
    __syncthreads();
    if (threadIdx.x == 0)
        partial[blockIdx.x] = smem[0] + smem[1] + smem[2] + smem[3];
}

__global__ void reduce_kernel(const float* __restrict__ partial,
                              float* __restrict__ out) {
    float s = 0.0f;
    for (int i = threadIdx.x; i < NBLK; i += 256) s += partial[i];
    #pragma unroll
    for (int off = 32; off > 0; off >>= 1)
        s += __shfl_down(s, off, 64);
    __shared__ float smem[4];
    int lane = threadIdx.x & 63;
    int wave = threadIdx.x >> 6;
    if (lane == 0) smem[wave] = s;
    __syncthreads();
    if (threadIdx.x == 0)
        out[0] = (smem[0] + smem[1] + smem[2] + smem[3]) * (1.0f / (float)NPIX);
}

extern "C" void kernel_launch(void* const* d_in, const int* in_sizes, int n_in,
                              void* d_out, int out_size, void* d_ws, size_t ws_size,
                              hipStream_t stream) {
    const float* x = (const float*)d_in[0];
    const int* t = (const int*)d_in[1];
    float* out = (float*)d_out;
    float* partial = (float*)d_ws;  // NBLK floats = 8 KB

    fused_kernel<<<NBLK, 256, 0, stream>>>(x, t, partial);
    reduce_kernel<<<1, 256, 0, stream>>>(partial, out);
}